// Round 1
// baseline (446.729 us; speedup 1.0000x reference)
//
#include <hip/hip_runtime.h>
#include <math.h>

typedef __attribute__((ext_vector_type(8))) short short8;
typedef __attribute__((ext_vector_type(4))) float f32x4;
typedef __attribute__((ext_vector_type(4))) float float4v;
typedef __attribute__((ext_vector_type(4))) unsigned short ushort4v;

#define E_NUM 16

__constant__ int d_caps[E_NUM] = {1024,512,1024,256,1024,512,128,1024,512,1024,256,512,1024,128,64,512};
__constant__ int d_offs[E_NUM] = {0,1024,1536,2560,2816,3840,4352,4480,5504,6016,7040,7296,7808,8832,8960,9024};

__device__ __forceinline__ unsigned short bf16_of(float f){
  unsigned int u = __builtin_bit_cast(unsigned int, f);
  return (unsigned short)((u + 0x7FFFu + ((u >> 16) & 1u)) >> 16);
}

// C = A @ W^T per expert.  A: [tokens][KDIM] (fp32 or bf16), W: [E][NDIM][KDIM] fp32.
// Out: [tokens][NDIM]  (bf16 h with GELU, or fp32 with plain bias).
template<bool A_BF16, bool GELU_OUT, int NDIM, int KDIM, int LOG_NTN>
__global__ __launch_bounds__(256, 2)
void expert_gemm(const void* __restrict__ Av, const float* __restrict__ W,
                 const float* __restrict__ bias, void* __restrict__ Outv)
{
  __shared__ __align__(16) unsigned short smem[16384];   // 32 KB: A[2][128][32] | B[2][128][32]
  unsigned short* a_lds = smem;           // + buf*4096
  unsigned short* b_lds = smem + 8192;    // + buf*4096

  const int tid = threadIdx.x;
  const int bid = blockIdx.x;

  // ---- locate (expert, m0, n0) from compile-time caps ----
  int e = 0, m0 = 0, n0 = 0;
  {
    int acc = 0;
    #pragma unroll
    for (int i = 0; i < E_NUM; ++i) {
      int mt = (d_caps[i] + 127) >> 7;
      int nb = mt << LOG_NTN;
      if (bid >= acc && bid < acc + nb) {
        e = i;
        int loc = bid - acc;
        m0 = (loc >> LOG_NTN) * 128;
        n0 = (loc & ((1 << LOG_NTN) - 1)) * 128;
      }
      acc += nb;
    }
  }
  const int Me   = d_caps[e];
  const int tok0 = d_offs[e];
  const float* Wb = W + (size_t)e * NDIM * KDIM;

  // staging coords
  const int sr  = tid >> 3;          // 0..31  (fp32 rows)
  const int skq = (tid & 7) * 4;     // col in k (floats)
  const int hr  = tid >> 2;          // 0..63  (bf16-A rows)
  const int hc  = (tid & 3) * 8;     // col in k (bf16)

  const float*          Af = (const float*)Av;
  const unsigned short* Ah = (const unsigned short*)Av;

  float4v ra[4]; short8 ha[2]; float4v rb[4];

  auto load_tile = [&](int kt) {
    const int k0 = kt * 32;
    if (A_BF16) {
      #pragma unroll
      for (int i = 0; i < 2; ++i) {
        int grow = m0 + hr + 64 * i;
        if (grow < Me)
          ha[i] = *reinterpret_cast<const short8*>(Ah + (size_t)(tok0 + grow) * KDIM + k0 + hc);
        else
          ha[i] = (short8){0,0,0,0,0,0,0,0};
      }
    } else {
      #pragma unroll
      for (int i = 0; i < 4; ++i) {
        int grow = m0 + sr + 32 * i;
        if (grow < Me)
          ra[i] = *reinterpret_cast<const float4v*>(Af + (size_t)(tok0 + grow) * KDIM + k0 + skq);
        else
          ra[i] = (float4v){0.f,0.f,0.f,0.f};
      }
    }
    #pragma unroll
    for (int i = 0; i < 4; ++i) {
      int row = sr + 32 * i;
      rb[i] = *reinterpret_cast<const float4v*>(Wb + (size_t)(n0 + row) * KDIM + k0 + skq);
    }
  };

  auto write_tile = [&](int buf) {
    unsigned short* ab = a_lds + buf * 4096;
    unsigned short* bb = b_lds + buf * 4096;
    if (A_BF16) {
      #pragma unroll
      for (int i = 0; i < 2; ++i) {
        int row = hr + 64 * i;
        *reinterpret_cast<short8*>(ab + row * 32 + hc) = ha[i];
      }
    } else {
      #pragma unroll
      for (int i = 0; i < 4; ++i) {
        int row = sr + 32 * i;
        ushort4v p;
        p[0] = bf16_of(ra[i][0]); p[1] = bf16_of(ra[i][1]);
        p[2] = bf16_of(ra[i][2]); p[3] = bf16_of(ra[i][3]);
        *reinterpret_cast<ushort4v*>(ab + row * 32 + skq) = p;
      }
    }
    #pragma unroll
    for (int i = 0; i < 4; ++i) {
      int row = sr + 32 * i;
      ushort4v p;
      p[0] = bf16_of(rb[i][0]); p[1] = bf16_of(rb[i][1]);
      p[2] = bf16_of(rb[i][2]); p[3] = bf16_of(rb[i][3]);
      *reinterpret_cast<ushort4v*>(bb + row * 32 + skq) = p;
    }
  };

  // compute coords
  const int lane = tid & 63;
  const int wv   = tid >> 6;
  const int wm   = (wv >> 1) * 64;
  const int wn   = (wv & 1) * 64;
  const int lrow = lane & 15;
  const int kcol = (lane >> 4) * 8;

  f32x4 acc_[4][4];
  #pragma unroll
  for (int i = 0; i < 4; ++i)
    #pragma unroll
    for (int j = 0; j < 4; ++j)
      acc_[i][j] = (f32x4){0.f,0.f,0.f,0.f};

  load_tile(0);
  write_tile(0);
  __syncthreads();

  const int NT = KDIM / 32;
  for (int kt = 0; kt < NT; ++kt) {
    const int cur = kt & 1;
    if (kt + 1 < NT) load_tile(kt + 1);

    const unsigned short* ab = a_lds + cur * 4096;
    const unsigned short* bb = b_lds + cur * 4096;
    short8 afr[4], bfr[4];
    #pragma unroll
    for (int f = 0; f < 4; ++f)
      afr[f] = *reinterpret_cast<const short8*>(ab + (wm + f * 16 + lrow) * 32 + kcol);
    #pragma unroll
    for (int f = 0; f < 4; ++f)
      bfr[f] = *reinterpret_cast<const short8*>(bb + (wn + f * 16 + lrow) * 32 + kcol);

    #pragma unroll
    for (int i = 0; i < 4; ++i)
      #pragma unroll
      for (int j = 0; j < 4; ++j)
        acc_[i][j] = __builtin_amdgcn_mfma_f32_16x16x32_bf16(afr[i], bfr[j], acc_[i][j], 0, 0, 0);

    if (kt + 1 < NT) write_tile(cur ^ 1);
    __syncthreads();
  }

  // ---- epilogue ----
  float bv[4];
  #pragma unroll
  for (int f = 0; f < 4; ++f)
    bv[f] = bias[(size_t)e * NDIM + n0 + wn + f * 16 + lrow];

  if (GELU_OUT) {
    // bias + exact GELU -> bf16, transpose through LDS for coalesced 16B stores
    unsigned short* hout = smem;   // [128][128] bf16 = 32 KB (barrier already passed)
    #pragma unroll
    for (int i = 0; i < 4; ++i) {
      const int rbase = wm + i * 16 + (lane >> 4) * 4;
      #pragma unroll
      for (int j = 0; j < 4; ++j) {
        #pragma unroll
        for (int jj = 0; jj < 4; ++jj) {
          float xv = acc_[i][j][jj] + bv[j];
          float g  = 0.5f * xv * (1.0f + erff(xv * 0.70710678118654752f));
          hout[(rbase + jj) * 128 + wn + j * 16 + lrow] = bf16_of(g);
        }
      }
    }
    __syncthreads();
    unsigned short* Oh = (unsigned short*)Outv;
    #pragma unroll
    for (int it = 0; it < 8; ++it) {
      int row  = it * 16 + (tid >> 4);
      int c    = (tid & 15) * 8;
      int grow = m0 + row;
      if (grow < Me) {
        *reinterpret_cast<short8*>(Oh + (size_t)(tok0 + grow) * NDIM + n0 + c)
          = *reinterpret_cast<const short8*>(hout + row * 128 + c);
      }
    }
  } else {
    float* Of = (float*)Outv;
    #pragma unroll
    for (int i = 0; i < 4; ++i) {
      const int rbase = wm + i * 16 + (lane >> 4) * 4;
      #pragma unroll
      for (int jj = 0; jj < 4; ++jj) {
        int grow = m0 + rbase + jj;
        if (grow < Me) {
          #pragma unroll
          for (int j = 0; j < 4; ++j) {
            Of[(size_t)(tok0 + grow) * NDIM + n0 + wn + j * 16 + lrow] = acc_[i][j][jj] + bv[j];
          }
        }
      }
    }
  }
}

extern "C" void kernel_launch(void* const* d_in, const int* in_sizes, int n_in,
                              void* d_out, int out_size, void* d_ws, size_t ws_size,
                              hipStream_t stream)
{
  const float* x  = (const float*)d_in[0];
  const float* W1 = (const float*)d_in[1];
  const float* b1 = (const float*)d_in[2];
  const float* W2 = (const float*)d_in[3];
  const float* b2 = (const float*)d_in[4];
  float* out = (float*)d_out;
  unsigned short* h = (unsigned short*)d_ws;   // [9536][4096] bf16 = 78.1 MB

  constexpr int MT_TILES = 75;  // sum over experts of ceil(cap/128)

  // GEMM1: h = gelu(x @ W1^T + b1)   M=caps, N=4096, K=1024
  expert_gemm<false, true, 4096, 1024, 5><<<MT_TILES * 32, 256, 0, stream>>>(
      (const void*)x, W1, b1, (void*)h);

  // GEMM2: out = h @ W2^T + b2       M=caps, N=1024, K=4096
  expert_gemm<true, false, 1024, 4096, 3><<<MT_TILES * 8, 256, 0, stream>>>(
      (const void*)h, W2, b2, (void*)out);
}

// Round 2
// 443.548 us; speedup vs baseline: 1.0072x; 1.0072x over previous
//
#include <hip/hip_runtime.h>
#include <math.h>

typedef __attribute__((ext_vector_type(8))) short short8;
typedef __attribute__((ext_vector_type(4))) float f32x4;
typedef __attribute__((ext_vector_type(2))) unsigned int u32x2;

#define E_NUM 16
constexpr int CAPS[E_NUM] = {1024,512,1024,256,1024,512,128,1024,512,1024,256,512,1024,128,64,512};
constexpr int OFFS[E_NUM] = {0,1024,1536,2560,2816,3840,4352,4480,5504,6016,7040,7296,7808,8832,8960,9024};
constexpr int cdiv_(int a, int b){ return (a + b - 1) / b; }
constexpr int ilog2_(int v){ int l = 0; while ((1 << l) < v) ++l; return l; }

__device__ __forceinline__ unsigned int cvt_pk_bf16(float a, float b){
  unsigned int r;
  asm("v_cvt_pk_bf16_f32 %0, %1, %2" : "=v"(r) : "v"(a), "v"(b));
  return r;
}

// C = A @ W^T per expert.  A: [tokens][KDIM] (fp32 or bf16), W: [E][NDIM][KDIM] fp32.
// Out: bf16 h with GELU (TM=128), or fp32 with plain bias.
template<bool A_BF16, bool GELU_OUT, int TM, int NDIM, int KDIM, int LOG_GN, int NWG>
__global__ __launch_bounds__(256, 4)
void expert_gemm(const void* __restrict__ Av, const float* __restrict__ W,
                 const float* __restrict__ bias, void* __restrict__ Outv)
{
  constexpr int STR  = 40;            // padded LDS row stride in shorts (80 B, 16B-aligned, ~2-way banks)
  constexpr int A_SZ = TM * STR;      // per-buffer A (shorts)
  constexpr int B_SZ = 128 * STR;     // per-buffer B
  constexpr int GN   = 1 << LOG_GN;   // n-panels per reuse group
  constexpr int MFR  = TM / 32;       // 16-row A-frags per wave
  static_assert(NWG % 8 == 0, "grid must be divisible by 8 for XCD swizzle");

  __shared__ __align__(16) unsigned short smem[2 * A_SZ + 2 * B_SZ];

  const int tid  = threadIdx.x;
  const int braw = blockIdx.x;
  // bijective XCD swizzle: consecutive logical tiles stay on one XCD
  const int t = (braw & 7) * (NWG / 8) + (braw >> 3);

  // ---- locate (expert, m0, n0): m-fastest within groups of GN n-panels ----
  int m0 = 0, n0 = 0, Me = 0, tok0 = 0;
  size_t wbase = 0, bbase = 0;
  {
    int acc0 = 0;
    #pragma unroll
    for (int i = 0; i < E_NUM; ++i) {
      const int mt  = cdiv_(CAPS[i], TM);
      const int lmt = ilog2_(mt);
      const int nb  = mt * (NDIM / 128);
      if (t >= acc0 && t < acc0 + nb) {
        const int loc = t - acc0;
        const int g   = loc >> (lmt + LOG_GN);
        const int rem = loc & ((mt << LOG_GN) - 1);
        m0   = (rem >> LOG_GN) * TM;
        n0   = ((g << LOG_GN) | (rem & (GN - 1))) * 128;
        Me   = CAPS[i];
        tok0 = OFFS[i];
        wbase = (size_t)i * NDIM * KDIM;
        bbase = (size_t)i * NDIM;
      }
      acc0 += nb;
    }
  }
  const float* Wb = W + wbase;

  // staging coords
  const int sr  = tid >> 3;          // 0..31  (fp32 rows)
  const int skq = (tid & 7) * 4;     // col (floats / shorts)
  const int hr  = tid >> 2;          // 0..63  (bf16-A rows)
  const int hc  = (tid & 3) * 8;     // col (shorts)

  const float*          Af = (const float*)Av;
  const unsigned short* Ah = (const unsigned short*)Av;

  f32x4 ra[4]; short8 ha[2]; f32x4 rb[4];

  auto load_tile = [&](int kt) {
    const int k0 = kt * 32;
    if constexpr (A_BF16) {
      #pragma unroll
      for (int i = 0; i < TM / 64; ++i)
        ha[i] = *reinterpret_cast<const short8*>(
            Ah + (size_t)(tok0 + m0 + hr + 64 * i) * KDIM + k0 + hc);
    } else {
      #pragma unroll
      for (int i = 0; i < TM / 32; ++i)
        ra[i] = *reinterpret_cast<const f32x4*>(
            Af + (size_t)(tok0 + m0 + sr + 32 * i) * KDIM + k0 + skq);
    }
    #pragma unroll
    for (int i = 0; i < 4; ++i)
      rb[i] = *reinterpret_cast<const f32x4*>(
          Wb + (size_t)(n0 + sr + 32 * i) * KDIM + k0 + skq);
  };

  auto write_tile = [&](int buf) {
    unsigned short* ab = smem + buf * A_SZ;
    unsigned short* bb = smem + 2 * A_SZ + buf * B_SZ;
    if constexpr (A_BF16) {
      #pragma unroll
      for (int i = 0; i < TM / 64; ++i)
        *reinterpret_cast<short8*>(ab + (hr + 64 * i) * STR + hc) = ha[i];
    } else {
      #pragma unroll
      for (int i = 0; i < TM / 32; ++i) {
        u32x2 p;
        p[0] = cvt_pk_bf16(ra[i][0], ra[i][1]);
        p[1] = cvt_pk_bf16(ra[i][2], ra[i][3]);
        *reinterpret_cast<u32x2*>(ab + (sr + 32 * i) * STR + skq) = p;
      }
    }
    #pragma unroll
    for (int i = 0; i < 4; ++i) {
      u32x2 p;
      p[0] = cvt_pk_bf16(rb[i][0], rb[i][1]);
      p[1] = cvt_pk_bf16(rb[i][2], rb[i][3]);
      *reinterpret_cast<u32x2*>(bb + (sr + 32 * i) * STR + skq) = p;
    }
  };

  // compute coords
  const int lane = tid & 63;
  const int wv   = tid >> 6;
  const int wm   = (wv >> 1) * (TM / 2);
  const int wn   = (wv & 1) * 64;
  const int lrow = lane & 15;
  const int kcol = (lane >> 4) * 8;

  f32x4 acc_[MFR][4];
  #pragma unroll
  for (int i = 0; i < MFR; ++i)
    #pragma unroll
    for (int j = 0; j < 4; ++j)
      acc_[i][j] = (f32x4){0.f, 0.f, 0.f, 0.f};

  load_tile(0);
  write_tile(0);
  __syncthreads();

  constexpr int NT = KDIM / 32;
  for (int kt = 0; kt < NT; ++kt) {
    const int cur = kt & 1;
    if (kt + 1 < NT) load_tile(kt + 1);   // issue next-tile loads early

    const unsigned short* ab = smem + cur * A_SZ;
    const unsigned short* bb = smem + 2 * A_SZ + cur * B_SZ;
    short8 afr[MFR], bfr[4];
    #pragma unroll
    for (int f = 0; f < MFR; ++f)
      afr[f] = *reinterpret_cast<const short8*>(ab + (wm + f * 16 + lrow) * STR + kcol);
    #pragma unroll
    for (int f = 0; f < 4; ++f)
      bfr[f] = *reinterpret_cast<const short8*>(bb + (wn + f * 16 + lrow) * STR + kcol);

    #pragma unroll
    for (int i = 0; i < MFR; ++i)
      #pragma unroll
      for (int j = 0; j < 4; ++j)
        acc_[i][j] = __builtin_amdgcn_mfma_f32_16x16x32_bf16(afr[i], bfr[j], acc_[i][j], 0, 0, 0);

    if (kt + 1 < NT) write_tile(cur ^ 1); // HBM latency hidden under the MFMAs above
    __syncthreads();
  }

  // ---- epilogue ----
  float bv[4];
  #pragma unroll
  for (int f = 0; f < 4; ++f)
    bv[f] = bias[bbase + n0 + wn + f * 16 + lrow];

  if constexpr (GELU_OUT) {
    static_assert(TM == 128, "GELU path assumes 128-row tiles");
    // bias + exact GELU -> bf16, transpose through LDS for coalesced 16B stores
    unsigned short* hout = smem;   // [128][128] bf16 = 32 KB (fits in 40 KB)
    #pragma unroll
    for (int i = 0; i < MFR; ++i) {
      const int rbase = wm + i * 16 + (lane >> 4) * 4;
      #pragma unroll
      for (int j = 0; j < 4; ++j) {
        #pragma unroll
        for (int jj = 0; jj < 4; ++jj) {
          float xv = acc_[i][j][jj] + bv[j];
          float g  = 0.5f * xv * (1.0f + erff(xv * 0.70710678118654752f));
          hout[(rbase + jj) * 128 + wn + j * 16 + lrow] = (unsigned short)(cvt_pk_bf16(g, g) & 0xFFFFu);
        }
      }
    }
    __syncthreads();
    unsigned short* Oh = (unsigned short*)Outv;
    #pragma unroll
    for (int it = 0; it < 8; ++it) {
      int row  = it * 16 + (tid >> 4);
      int c    = (tid & 15) * 8;
      int grow = m0 + row;
      if (grow < Me) {
        *reinterpret_cast<short8*>(Oh + (size_t)(tok0 + grow) * NDIM + n0 + c)
          = *reinterpret_cast<const short8*>(hout + row * 128 + c);
      }
    }
  } else {
    float* Of = (float*)Outv;
    #pragma unroll
    for (int i = 0; i < MFR; ++i) {
      const int rbase = wm + i * 16 + (lane >> 4) * 4;
      #pragma unroll
      for (int jj = 0; jj < 4; ++jj) {
        int grow = m0 + rbase + jj;
        if (grow < Me) {
          #pragma unroll
          for (int j = 0; j < 4; ++j) {
            Of[(size_t)(tok0 + grow) * NDIM + n0 + wn + j * 16 + lrow] = acc_[i][j][jj] + bv[j];
          }
        }
      }
    }
  }
}

extern "C" void kernel_launch(void* const* d_in, const int* in_sizes, int n_in,
                              void* d_out, int out_size, void* d_ws, size_t ws_size,
                              hipStream_t stream)
{
  const float* x  = (const float*)d_in[0];
  const float* W1 = (const float*)d_in[1];
  const float* b1 = (const float*)d_in[2];
  const float* W2 = (const float*)d_in[3];
  const float* b2 = (const float*)d_in[4];
  float* out = (float*)d_out;
  unsigned short* h = (unsigned short*)d_ws;   // [9536][4096] bf16 = 78.1 MB

  // GEMM1: h = gelu(x @ W1^T + b1)   tiles 128x128, Σceil(cap/128)=75 m-tiles × 32 n-tiles
  expert_gemm<false, true, 128, 4096, 1024, 2, 75 * 32>
      <<<75 * 32, 256, 0, stream>>>((const void*)x, W1, b1, (void*)h);

  // GEMM2: out = h @ W2^T + b2       tiles 64x128, Σceil(cap/64)=149 m-tiles × 8 n-tiles
  expert_gemm<true, false, 64, 1024, 4096, 1, 149 * 8>
      <<<149 * 8, 256, 0, stream>>>((const void*)h, W2, b2, (void*)out);
}

// Round 3
// 398.235 us; speedup vs baseline: 1.1218x; 1.1138x over previous
//
#include <hip/hip_runtime.h>
#include <math.h>

typedef __attribute__((ext_vector_type(8))) short short8;
typedef __attribute__((ext_vector_type(4))) float f32x4;
typedef __attribute__((ext_vector_type(2))) unsigned int u32x2;

#define E_NUM 16
constexpr int CAPS[E_NUM] = {1024,512,1024,256,1024,512,128,1024,512,1024,256,512,1024,128,64,512};
constexpr int OFFS[E_NUM] = {0,1024,1536,2560,2816,3840,4352,4480,5504,6016,7040,7296,7808,8832,8960,9024};
constexpr int cdiv_(int a, int b){ return (a + b - 1) / b; }
constexpr int ilog2_(int v){ int l = 0; while ((1 << l) < v) ++l; return l; }

__device__ __forceinline__ unsigned int cvt_pk_bf16(float a, float b){
  unsigned int r;
  asm("v_cvt_pk_bf16_f32 %0, %1, %2" : "=v"(r) : "v"(a), "v"(b));
  return r;
}

typedef __attribute__((address_space(1))) const unsigned char gas_u8;
typedef __attribute__((address_space(3))) unsigned char las_u8;
__device__ __forceinline__ void gl_lds16(const void* g, void* l){
  __builtin_amdgcn_global_load_lds((gas_u8*)g, (las_u8*)l, 16, 0, 0);
}

// x fp32 -> bf16 (RNE), 8 elems/thread, grid-stride
__global__ __launch_bounds__(256) void cvt_bf16_kernel(const float* __restrict__ x,
                                                       unsigned short* __restrict__ xb, int n8)
{
  int i = blockIdx.x * blockDim.x + threadIdx.x;
  const int stride = gridDim.x * blockDim.x;
  for (; i < n8; i += stride) {
    f32x4 a = *reinterpret_cast<const f32x4*>(x + (size_t)i * 8);
    f32x4 b = *reinterpret_cast<const f32x4*>(x + (size_t)i * 8 + 4);
    u32x2 lo, hi;
    lo[0] = cvt_pk_bf16(a[0], a[1]); lo[1] = cvt_pk_bf16(a[2], a[3]);
    hi[0] = cvt_pk_bf16(b[0], b[1]); hi[1] = cvt_pk_bf16(b[2], b[3]);
    *reinterpret_cast<u32x2*>(xb + (size_t)i * 8)     = lo;
    *reinterpret_cast<u32x2*>(xb + (size_t)i * 8 + 4) = hi;
  }
}

// C = A @ W^T per expert.  A: [tokens][KDIM] (bf16 via global_load_lds, or fp32 reg-staged).
// W: [E][NDIM][KDIM] fp32 (reg-staged + cvt).  Out: bf16 h with GELU, or fp32 + bias.
// LDS rows are 32 bf16 (64 B); 16B-blocks XOR-swizzled: phys_byte = byte ^ ((row&3)<<4).
template<bool A_GLDS, bool GELU_OUT, int TM, int NDIM, int KDIM, int LOG_GN, int NWG>
__global__ __launch_bounds__(256, 4)
void expert_gemm(const void* __restrict__ Av, const float* __restrict__ W,
                 const float* __restrict__ bias, void* __restrict__ Outv)
{
  constexpr int A_SZ = TM * 32;       // shorts per A buffer
  constexpr int B_SZ = 128 * 32;      // shorts per B buffer
  constexpr int GN   = 1 << LOG_GN;
  constexpr int MFR  = TM / 32;       // A-frags per wave
  static_assert(NWG % 8 == 0, "grid must be divisible by 8 for XCD swizzle");
  static_assert(!GELU_OUT || 2 * (A_SZ + B_SZ) >= 128 * 128, "GELU transpose needs 32KB");

  __shared__ __align__(16) unsigned short smem[2 * A_SZ + 2 * B_SZ];

  const int tid  = threadIdx.x;
  const int braw = blockIdx.x;
  const int t = (braw & 7) * (NWG / 8) + (braw >> 3);   // bijective XCD swizzle

  // ---- locate (expert, m0, n0): m-fastest within groups of GN n-panels ----
  int m0 = 0, n0 = 0, Me = 0, tok0 = 0;
  size_t wbase = 0, bbase = 0;
  {
    int acc0 = 0;
    #pragma unroll
    for (int i = 0; i < E_NUM; ++i) {
      const int mt  = cdiv_(CAPS[i], TM);
      const int lmt = ilog2_(mt);
      const int nb  = mt * (NDIM / 128);
      if (t >= acc0 && t < acc0 + nb) {
        const int loc = t - acc0;
        const int g   = loc >> (lmt + LOG_GN);
        const int rem = loc & ((mt << LOG_GN) - 1);
        m0   = (rem >> LOG_GN) * TM;
        n0   = ((g << LOG_GN) | (rem & (GN - 1))) * 128;
        Me   = CAPS[i];
        tok0 = OFFS[i];
        wbase = (size_t)i * NDIM * KDIM;
        bbase = (size_t)i * NDIM;
      }
      acc0 += nb;
    }
  }
  const float* Wb = W + wbase;

  const int lane = tid & 63;
  const int wv   = tid >> 6;
  const int sr   = tid >> 3;          // 0..31 staging row
  const int sc   = (tid & 7) * 8;     // staging byte col (0..56)
  const int spc  = sc ^ ((sr & 3) << 4);  // swizzled byte col (same for row sr+32i: (row&3) invariant)

  const unsigned short* Ah = (const unsigned short*)Av;
  const float*          Af = (const float*)Av;

  f32x4 ra[MFR]; f32x4 rb[4];

  // --- B: global fp32 -> regs ---
  auto loadB = [&](int kt) {
    const int k0 = kt * 32;
    #pragma unroll
    for (int i = 0; i < 4; ++i)
      rb[i] = *reinterpret_cast<const f32x4*>(Wb + (size_t)(n0 + sr + 32 * i) * KDIM + k0 + (sc >> 1));
  };
  auto writeB = [&](int buf) {
    char* bb = (char*)(smem + 2 * A_SZ + buf * B_SZ);
    #pragma unroll
    for (int i = 0; i < 4; ++i) {
      u32x2 p;
      p[0] = cvt_pk_bf16(rb[i][0], rb[i][1]);
      p[1] = cvt_pk_bf16(rb[i][2], rb[i][3]);
      *reinterpret_cast<u32x2*>(bb + (sr + 32 * i) * 64 + spc) = p;
    }
  };

  // --- A: bf16 global -> LDS direct (pre-swizzled source), or fp32 reg-staged ---
  auto stageA_glds = [&](int buf, int kt) {
    constexpr int AI = TM / 64;                 // gl_lds16 instrs per wave
    const unsigned short* Ag = Ah + (size_t)(tok0 + m0) * KDIM + kt * 32;
    #pragma unroll
    for (int j = 0; j < AI; ++j) {
      const int rbase = wv * (AI * 16) + j * 16;
      const int r     = rbase + (lane >> 2);
      const int gblk  = (lane & 3) ^ (r & 3);   // pre-swizzle global 16B-block
      gl_lds16((const void*)(Ag + (size_t)r * KDIM + gblk * 8),
               (void*)(smem + buf * A_SZ + rbase * 32));
    }
  };
  auto loadA_reg = [&](int kt) {
    const int k0 = kt * 32;
    #pragma unroll
    for (int i = 0; i < MFR; ++i)
      ra[i] = *reinterpret_cast<const f32x4*>(Af + (size_t)(tok0 + m0 + sr + 32 * i) * KDIM + k0 + (sc >> 1));
  };
  auto writeA_reg = [&](int buf) {
    char* ab = (char*)(smem + buf * A_SZ);
    #pragma unroll
    for (int i = 0; i < MFR; ++i) {
      u32x2 p;
      p[0] = cvt_pk_bf16(ra[i][0], ra[i][1]);
      p[1] = cvt_pk_bf16(ra[i][2], ra[i][3]);
      *reinterpret_cast<u32x2*>(ab + (sr + 32 * i) * 64 + spc) = p;
    }
  };

  // compute coords
  const int wm   = (wv >> 1) * (TM / 2);
  const int wn   = (wv & 1) * 64;
  const int lrow = lane & 15;
  const int fcs  = ((lane >> 4) << 4) ^ ((lane & 3) << 4);  // swizzled frag byte col (row&3 == lane&3)

  f32x4 acc_[MFR][4];
  #pragma unroll
  for (int i = 0; i < MFR; ++i)
    #pragma unroll
    for (int j = 0; j < 4; ++j)
      acc_[i][j] = (f32x4){0.f, 0.f, 0.f, 0.f};

  // prologue: tile 0
  loadB(0);
  if constexpr (A_GLDS) stageA_glds(0, 0); else { loadA_reg(0); writeA_reg(0); }
  writeB(0);
  __syncthreads();

  constexpr int NT = KDIM / 32;
  for (int kt = 0; kt < NT; ++kt) {
    const int cur = kt & 1;
    if (kt + 1 < NT) {
      loadB(kt + 1);                         // B regs first (counted-vmcnt friendly)
      if constexpr (A_GLDS) stageA_glds(cur ^ 1, kt + 1);
      else                  loadA_reg(kt + 1);
    }

    const char* ab = (const char*)(smem + cur * A_SZ);
    const char* bb = (const char*)(smem + 2 * A_SZ + cur * B_SZ);
    short8 afr[MFR], bfr[4];
    #pragma unroll
    for (int f = 0; f < MFR; ++f)
      afr[f] = *reinterpret_cast<const short8*>(ab + (wm + f * 16 + lrow) * 64 + fcs);
    #pragma unroll
    for (int f = 0; f < 4; ++f)
      bfr[f] = *reinterpret_cast<const short8*>(bb + (wn + f * 16 + lrow) * 64 + fcs);

    #pragma unroll
    for (int i = 0; i < MFR; ++i)
      #pragma unroll
      for (int j = 0; j < 4; ++j)
        acc_[i][j] = __builtin_amdgcn_mfma_f32_16x16x32_bf16(afr[i], bfr[j], acc_[i][j], 0, 0, 0);

    if (kt + 1 < NT) {
      writeB(cur ^ 1);
      if constexpr (!A_GLDS) writeA_reg(cur ^ 1);
    }
    __syncthreads();
  }

  // ---- epilogue ----
  float bv[4];
  #pragma unroll
  for (int f = 0; f < 4; ++f)
    bv[f] = bias[bbase + n0 + wn + f * 16 + lrow];

  if constexpr (GELU_OUT) {
    static_assert(TM == 128, "GELU path assumes 128-row tiles");
    unsigned short* hout = smem;   // [128][128] bf16 = 32 KB
    #pragma unroll
    for (int i = 0; i < MFR; ++i) {
      const int rbase = wm + i * 16 + (lane >> 4) * 4;
      #pragma unroll
      for (int j = 0; j < 4; ++j) {
        #pragma unroll
        for (int jj = 0; jj < 4; ++jj) {
          float xv = acc_[i][j][jj] + bv[j];
          float g  = 0.5f * xv * (1.0f + erff(xv * 0.70710678118654752f));
          hout[(rbase + jj) * 128 + wn + j * 16 + lrow] = (unsigned short)(cvt_pk_bf16(g, g) & 0xFFFFu);
        }
      }
    }
    __syncthreads();
    unsigned short* Oh = (unsigned short*)Outv;
    #pragma unroll
    for (int it = 0; it < 8; ++it) {
      int row  = it * 16 + (tid >> 4);
      int c    = (tid & 15) * 8;
      int grow = m0 + row;
      if (grow < Me) {
        *reinterpret_cast<short8*>(Oh + (size_t)(tok0 + grow) * NDIM + n0 + c)
          = *reinterpret_cast<const short8*>(hout + row * 128 + c);
      }
    }
  } else {
    float* Of = (float*)Outv;
    #pragma unroll
    for (int i = 0; i < MFR; ++i) {
      const int rbase = wm + i * 16 + (lane >> 4) * 4;
      #pragma unroll
      for (int jj = 0; jj < 4; ++jj) {
        int grow = m0 + rbase + jj;
        if (grow < Me) {
          #pragma unroll
          for (int j = 0; j < 4; ++j) {
            Of[(size_t)(tok0 + grow) * NDIM + n0 + wn + j * 16 + lrow] = acc_[i][j][jj] + bv[j];
          }
        }
      }
    }
  }
}

extern "C" void kernel_launch(void* const* d_in, const int* in_sizes, int n_in,
                              void* d_out, int out_size, void* d_ws, size_t ws_size,
                              hipStream_t stream)
{
  const float* x  = (const float*)d_in[0];
  const float* W1 = (const float*)d_in[1];
  const float* b1 = (const float*)d_in[2];
  const float* W2 = (const float*)d_in[3];
  const float* b2 = (const float*)d_in[4];
  float* out = (float*)d_out;

  constexpr size_t H_BYTES  = (size_t)9536 * 4096 * 2;   // h bf16
  constexpr size_t XB_BYTES = (size_t)9536 * 1024 * 2;   // x bf16
  unsigned short* h  = (unsigned short*)d_ws;
  unsigned short* xb = (unsigned short*)((char*)d_ws + H_BYTES);

  const bool use_xb = ws_size >= H_BYTES + XB_BYTES;

  if (use_xb) {
    cvt_bf16_kernel<<<2048, 256, 0, stream>>>(x, xb, 9536 * 1024 / 8);
    // GEMM1: h = gelu(x @ W1^T + b1), 128x128 tiles, GN=4
    expert_gemm<true, true, 128, 4096, 1024, 2, 75 * 32>
        <<<75 * 32, 256, 0, stream>>>((const void*)xb, W1, b1, (void*)h);
  } else {
    expert_gemm<false, true, 128, 4096, 1024, 2, 75 * 32>
        <<<75 * 32, 256, 0, stream>>>((const void*)x, W1, b1, (void*)h);
  }

  // GEMM2: out = h @ W2^T + b2, 64x128 tiles, GN=1 (2MB W2 panel per L2)
  expert_gemm<true, false, 64, 1024, 4096, 0, 149 * 8>
      <<<149 * 8, 256, 0, stream>>>((const void*)h, W2, b2, (void*)out);
}